// Round 13
// baseline (456.630 us; speedup 1.0000x reference)
//
#include <hip/hip_runtime.h>
#include <hip/hip_bf16.h>
#include <cstdint>
#include <cstddef>

#define D_MODEL   1024
#define NUM_HEADS 16
#define HEAD_DIM  64
#define SEQ       2048
#define BATCH     4
#define BH        (BATCH*NUM_HEADS)   // 64
#define MROWS     (BATCH*SEQ)         // 8192

typedef _Float16 half8  __attribute__((ext_vector_type(8)));
typedef _Float16 half4v __attribute__((ext_vector_type(4)));
typedef float    floatx4 __attribute__((ext_vector_type(4)));

// ---------------------------------------------------------------------------
// async global -> LDS, 16 bytes per lane. LDS base must be wave-uniform;
// HW writes lds_base + lane*16 (LDS side contiguous; global side per-lane).
// ---------------------------------------------------------------------------
__device__ inline void gld_lds16(const void* g, void* l) {
    __builtin_amdgcn_global_load_lds(
        (__attribute__((address_space(1))) void*)g,
        (__attribute__((address_space(3))) void*)l,
        16, 0, 0);
}

// ---------------------------------------------------------------------------
// RoPE cos/sin table [s][p], p in [0,32): angle = s * 10000^(-p/32), fp64.
// ---------------------------------------------------------------------------
__global__ void rope_table(float2* __restrict__ tab) {
    const int i = blockIdx.x * blockDim.x + threadIdx.x;   // SEQ*32
    const int p = i & 31, s = i >> 5;
    const double inv = pow(10000.0, -(double)p / 32.0);
    const double ang = (double)s * inv;
    tab[i] = make_float2((float)cos(ang), (float)sin(ang));
}

// ---------------------------------------------------------------------------
// fp32 -> split f16 (hi + lo residual) for x, 4-wide. v ~= hi + lo to ~2^-22.
// ---------------------------------------------------------------------------
__global__ void f32_split_f16(const float* __restrict__ in,
                              _Float16* __restrict__ hi,
                              _Float16* __restrict__ lo, int n4) {
    int i = blockIdx.x * blockDim.x + threadIdx.x;
    if (i >= n4) return;
    float4 v = ((const float4*)in)[i];
    half4v h = { (_Float16)v.x, (_Float16)v.y, (_Float16)v.z, (_Float16)v.w };
    half4v l = { (_Float16)(v.x - (float)h.x), (_Float16)(v.y - (float)h.y),
                 (_Float16)(v.z - (float)h.z), (_Float16)(v.w - (float)h.w) };
    ((half4v*)hi)[i] = h;
    ((half4v*)lo)[i] = l;
}

// ---------------------------------------------------------------------------
// All 4 weight converts in one dispatch: qw,kw -> split hi/lo; vw,ow -> hi.
// ---------------------------------------------------------------------------
__global__ void conv_weights(const float* __restrict__ qw, const float* __restrict__ kw,
                             const float* __restrict__ vw, const float* __restrict__ ow,
                             _Float16* __restrict__ qwh, _Float16* __restrict__ qwl,
                             _Float16* __restrict__ kwh, _Float16* __restrict__ kwl,
                             _Float16* __restrict__ vwh, _Float16* __restrict__ owh) {
    const int i = blockIdx.x * blockDim.x + threadIdx.x;
    const int which = i >> 18;              // 262144 float4 per tensor
    const int j = i & 262143;
    const float4 v = ((const float4*)(which == 0 ? qw : which == 1 ? kw :
                                      which == 2 ? vw : ow))[j];
    half4v h = { (_Float16)v.x, (_Float16)v.y, (_Float16)v.z, (_Float16)v.w };
    if (which < 2) {
        half4v l = { (_Float16)(v.x - (float)h.x), (_Float16)(v.y - (float)h.y),
                     (_Float16)(v.z - (float)h.z), (_Float16)(v.w - (float)h.w) };
        ((half4v*)(which ? kwh : qwh))[j] = h;
        ((half4v*)(which ? kwl : qwl))[j] = l;
    } else {
        ((half4v*)(which == 2 ? vwh : owh))[j] = h;
    }
}

// ---------------------------------------------------------------------------
// Plain GEMM: C[m,n] = sum_k A[m,k]*B[n,k], fp32 out. Output projection.
// Double-buffered LDS (2x16KB), ONE barrier per K-step.
// ---------------------------------------------------------------------------
__global__ __launch_bounds__(256)
void gemm_bt(const _Float16* __restrict__ A, const _Float16* __restrict__ B,
             float* __restrict__ Cout, int M, int N, int K) {
    __shared__ _Float16 AB[2][2][128*32];    // [buf][A/B] 32KB

    const int nb  = N >> 7;
    const int nwg = gridDim.x;
    int lb = blockIdx.x;
    if ((nwg & 7) == 0)                      // chunked XCD swizzle (m157)
        lb = (blockIdx.x & 7) * (nwg >> 3) + (blockIdx.x >> 3);
    const int bx = lb % nb;
    const int by = lb / nb;
    const int m0 = by << 7, n0 = bx << 7;

    const int t    = threadIdx.x;
    const int w    = t >> 6;
    const int lane = t & 63;
    const int r    = lane & 15;
    const int quad = lane >> 4;
    const int wm   = (w >> 1) << 6;
    const int wn   = (w & 1) << 6;

    const int srow = lane >> 2;
    const int scol = (lane & 3) << 3;

    floatx4 acc[4][4];
    #pragma unroll
    for (int i = 0; i < 4; i++)
        #pragma unroll
        for (int j = 0; j < 4; j++)
            acc[i][j] = (floatx4){0.f, 0.f, 0.f, 0.f};

    auto stageAB = [&](int buf, int kk) {
        #pragma unroll
        for (int p = 0; p < 2; ++p) {
            const int rbase = p*64 + w*16;
            gld_lds16(&A[(size_t)(m0 + rbase + srow)*K + kk + scol], &AB[buf][0][rbase*32]);
            gld_lds16(&B[(size_t)(n0 + rbase + srow)*K + kk + scol], &AB[buf][1][rbase*32]);
        }
    };

    stageAB(0, 0);                           // prologue
    int cur = 0;
    for (int k0 = 0; k0 < K; k0 += 32) {
        __syncthreads();                     // stage(k0,cur) landed; prev reads done
        if (k0 + 32 < K) stageAB(cur ^ 1, k0 + 32);   // hides under reads+MFMA

        const _Float16* As = AB[cur][0];
        const _Float16* Bs = AB[cur][1];
        half8 af[4], bf[4];
        #pragma unroll
        for (int i = 0; i < 4; i++)
            af[i] = *(const half8*)&As[(wm + i*16 + r)*32 + quad*8];
        #pragma unroll
        for (int j = 0; j < 4; j++)
            bf[j] = *(const half8*)&Bs[(wn + j*16 + r)*32 + quad*8];

        #pragma unroll
        for (int i = 0; i < 4; i++)
            #pragma unroll
            for (int j = 0; j < 4; j++)
                acc[i][j] = __builtin_amdgcn_mfma_f32_16x16x32_f16(
                                af[i], bf[j], acc[i][j], 0, 0, 0);
        cur ^= 1;
    }

    #pragma unroll
    for (int i = 0; i < 4; i++)
        #pragma unroll
        for (int j = 0; j < 4; j++)
            #pragma unroll
            for (int v = 0; v < 4; v++) {
                const int m = m0 + wm + i*16 + quad*4 + v;
                const int n = n0 + wn + j*16 + r;
                Cout[(size_t)m*N + n] = acc[i][j][v];
            }
}

// ---------------------------------------------------------------------------
// Fused Q/K/V projection — split into QK / V dispatches (kept: flash stays
// visible in rocprof top-5). Kernel body unchanged; bx = bxoff + lb%nt.
// ---------------------------------------------------------------------------
__global__ __launch_bounds__(256)
void gemm_qkv(const _Float16* __restrict__ Axh, const _Float16* __restrict__ Axl,
              const _Float16* __restrict__ qwh, const _Float16* __restrict__ qwl,
              const _Float16* __restrict__ kwh, const _Float16* __restrict__ kwl,
              const _Float16* __restrict__ vwh,
              _Float16* __restrict__ Qhi, _Float16* __restrict__ Qlo,
              _Float16* __restrict__ Khi, _Float16* __restrict__ Klo,
              _Float16* __restrict__ Vt,  const float2* __restrict__ tab,
              int bxoff, int nt) {
    __shared__ _Float16 smem[2][4][4096];  // 64KB: [buf][plane: Ah,Al,Bh,Bl][8KB]

    // chunked XCD swizzle (nwg %8==0): consecutive lb chunks per XCD.
    const int nwg = gridDim.x;
    const int lb  = (blockIdx.x & 7) * (nwg >> 3) + (blockIdx.x >> 3);
    const int bx  = bxoff + lb % nt;
    const int by  = lb / nt;
    const int wt  = bx >> 3;               // 0=Q, 1=K, 2=V
    const int n0  = (bx & 7) << 7;         // within this weight's 1024 cols
    const int m0  = by << 7;

    const _Float16* Bh = (wt == 0) ? qwh : (wt == 1) ? kwh : vwh;
    const _Float16* Bl = (wt == 0) ? qwl : kwl;      // unused when wt==2

    const int t    = threadIdx.x;
    const int w    = t >> 6;
    const int lane = t & 63;
    const int r    = lane & 15;
    const int quad = lane >> 4;
    const int wm   = (w >> 1) << 6;
    const int wn   = (w & 1) << 6;

    const int srow = lane >> 2;
    const int scol = (lane & 3) << 3;

    floatx4 acc[4][4];
    #pragma unroll
    for (int i = 0; i < 4; i++)
        #pragma unroll
        for (int j = 0; j < 4; j++)
            acc[i][j] = (floatx4){0.f, 0.f, 0.f, 0.f};

    auto stage_k = [&](int buf, int kk) {
        #pragma unroll
        for (int p = 0; p < 2; ++p) {
            const int rbase = p*64 + w*16;
            const size_t ga = (size_t)(m0 + rbase + srow)*1024 + kk + scol;
            const size_t gb = (size_t)(n0 + rbase + srow)*1024 + kk + scol;
            gld_lds16(&Axh[ga], &smem[buf][0][rbase*32]);
            gld_lds16(&Bh [gb], &smem[buf][2][rbase*32]);
            if (wt < 2) {
                gld_lds16(&Axl[ga], &smem[buf][1][rbase*32]);
                gld_lds16(&Bl [gb], &smem[buf][3][rbase*32]);
            }
        }
    };

    stage_k(0, 0);                         // prologue
    int cur = 0;
    for (int k0 = 0; k0 < 1024; k0 += 32) {
        __syncthreads();                   // stage(k0)->buf[cur] landed; prev reads done
        if (k0 + 32 < 1024) stage_k(cur ^ 1, k0 + 32);   // max-distance prefetch

        const _Float16* Ash = smem[cur][0];
        const _Float16* Asl = smem[cur][1];
        const _Float16* Bsh = smem[cur][2];
        const _Float16* Bsl = smem[cur][3];

        half8 ah[4], bh[4], al[4], bl[4];
        #pragma unroll
        for (int i = 0; i < 4; i++)
            ah[i] = *(const half8*)&Ash[(wm + i*16 + r)*32 + quad*8];
        #pragma unroll
        for (int j = 0; j < 4; j++)
            bh[j] = *(const half8*)&Bsh[(wn + j*16 + r)*32 + quad*8];
        if (wt < 2) {
            #pragma unroll
            for (int i = 0; i < 4; i++)
                al[i] = *(const half8*)&Asl[(wm + i*16 + r)*32 + quad*8];
            #pragma unroll
            for (int j = 0; j < 4; j++)
                bl[j] = *(const half8*)&Bsl[(wn + j*16 + r)*32 + quad*8];
        }

        if (wt < 2) {
            #pragma unroll
            for (int i = 0; i < 4; i++)
                #pragma unroll
                for (int j = 0; j < 4; j++) {
                    acc[i][j] = __builtin_amdgcn_mfma_f32_16x16x32_f16(
                                    ah[i], bh[j], acc[i][j], 0, 0, 0);
                    acc[i][j] = __builtin_amdgcn_mfma_f32_16x16x32_f16(
                                    ah[i], bl[j], acc[i][j], 0, 0, 0);
                    acc[i][j] = __builtin_amdgcn_mfma_f32_16x16x32_f16(
                                    al[i], bh[j], acc[i][j], 0, 0, 0);
                }
        } else {
            #pragma unroll
            for (int i = 0; i < 4; i++)
                #pragma unroll
                for (int j = 0; j < 4; j++)
                    acc[i][j] = __builtin_amdgcn_mfma_f32_16x16x32_f16(
                                    ah[i], bh[j], acc[i][j], 0, 0, 0);
        }
        cur ^= 1;
    }

    // ----- epilogue: per-wave LDS transpose + wide stores -----
    __syncthreads();                       // K-loop LDS traffic done; reuse as scratch
    float* sc = (float*)&smem[0][0][0] + w*1088;   // 16 rows x stride 68 fp32, per wave
    const int g  = lane & 7;               // 8-col group
    const int rw = lane >> 3;              // 0..7
    const int hh = (n0 + wn) >> 6;         // head fixed per wave (n0%128==0, wn 0/64)

    if (wt < 2) {
        _Float16* Chi = wt ? Khi : Qhi;
        _Float16* Clo = wt ? Klo : Qlo;
        #pragma unroll
        for (int i = 0; i < 4; i++) {
            #pragma unroll
            for (int j = 0; j < 4; j++)
                #pragma unroll
                for (int v = 0; v < 4; v++)
                    sc[(quad*4 + v)*68 + j*16 + r] = acc[i][j][v];
            // per-wave region; same-wave DS ops are in-order (Pl pattern)
            #pragma unroll
            for (int rg = 0; rg < 2; rg++) {
                const int row = rw + rg*8;
                const int m   = m0 + wm + i*16 + row;
                const int bb  = m >> 11, s_ = m & 2047;
                const float4 va = *(const float4*)&sc[row*68 + g*8];
                const float4 vb = *(const float4*)&sc[row*68 + g*8 + 4];
                const float vv[8] = {va.x, va.y, va.z, va.w,
                                     vb.x, vb.y, vb.z, vb.w};
                half8 hv, lv;
                #pragma unroll
                for (int p2 = 0; p2 < 4; p2++) {
                    const float2 cs = tab[s_*32 + g*4 + p2];
                    const float e0 = vv[2*p2], o0 = vv[2*p2+1];
                    const float re = e0*cs.x - o0*cs.y;
                    const float ro = e0*cs.y + o0*cs.x;
                    const _Float16 rh = (_Float16)re;
                    const _Float16 oh = (_Float16)ro;
                    hv[2*p2]   = rh; lv[2*p2]   = (_Float16)(re - (float)rh);
                    hv[2*p2+1] = oh; lv[2*p2+1] = (_Float16)(ro - (float)oh);
                }
                const size_t idx = ((((size_t)bb*NUM_HEADS + hh)*SEQ + s_) << 6) + g*8;
                *(half8*)&Chi[idx] = hv;
                *(half8*)&Clo[idx] = lv;
            }
        }
    } else {
        const int d = lane;                // 0..63, col within wave's 64
        #pragma unroll
        for (int i = 0; i < 4; i++) {
            #pragma unroll
            for (int j = 0; j < 4; j++)
                #pragma unroll
                for (int v = 0; v < 4; v++)
                    sc[(quad*4 + v)*68 + j*16 + r] = acc[i][j][v];
            #pragma unroll
            for (int rg = 0; rg < 2; rg++) {
                const int m  = m0 + wm + i*16 + rg*8;
                const int bb = m >> 11, s_ = m & 2047;
                half8 ov;
                #pragma unroll
                for (int rr = 0; rr < 8; rr++)
                    ov[rr] = (_Float16)sc[(rg*8 + rr)*68 + d];
                *(half8*)&Vt[((((size_t)bb*NUM_HEADS + hh)*HEAD_DIM + d) << 11) + s_] = ov;
            }
        }
    }
}

// ---------------------------------------------------------------------------
// Causal flash attention — round-16: MERGED K-FRAGMENT READS (regime-gated
// retry of R8's idea, now in the right regime).
// R12 audit: per CU ~357k cyc of LDS-pipe demand vs 315k duration — flash is
// LDS-read-throughput-saturated. Dominant term: both q-groups read IDENTICAL
// K-fragments (32 of ~58 LDS ops/wave-iter). R8's full merge regressed at
// 2 blocks/CU (latency-bound regime, +LDS +VGPR); now at 4 blocks/CU the
// kernel is BW-bound, so halving K reads pays. This merge is MINIMAL:
// S^T reads K-frags once -> 12 MFMAs (s0+s1); softmax/P/PV stay serial per
// group (single Pl strip reused — per-wave in-order DS; V-frags read per
// group). LDS ops/wave-iter 58->42 (-28%). LDS 39.9KB / 4 blocks kept;
// __launch_bounds__(256,4) pins VGPR<=128 (guards the 4-waves/SIMD cliff).
// R11 LPT scheduling restored (R12 pairing: +44% staging, +7.7us — reverted).
// ---------------------------------------------------------------------------
#define PSTR 72     // P strip stride in f16
#define KSTR 40     // K/V plane row stride in f16
__global__ __launch_bounds__(256, 4)
void flash_attn(const _Float16* __restrict__ Qhi, const _Float16* __restrict__ Qlo,
                const _Float16* __restrict__ Khi, const _Float16* __restrict__ Klo,
                const _Float16* __restrict__ Vt,  _Float16* __restrict__ AO) {
    // SB[plane][64*KSTR]: planes 0/1 = K hi d[0,32)/d[32,64),
    // 2/3 = K lo, 4/5 = V^T keys [0,32)/[32,64). 30KB, single-buffered.
    __shared__ _Float16 SB[6][64*KSTR];
    __shared__ _Float16 Pl[4][16*PSTR];

    const int t    = threadIdx.x;
    const int w    = t >> 6;
    const int lane = t & 63;
    const int r    = lane & 15;
    const int quad = lane >> 4;

    const int bx = blockIdx.x;
    const int bh = bx & 63;                 // 64 bh, fastest
    const int qb = 15 - (bx >> 6);          // 16 q-blocks of 128, longest first
    const int Q0 = qb << 7;
    const int q0a = Q0 + w*16;              // group 0 rows
    const int q0b = Q0 + 64 + w*16;         // group 1 rows
    const int b  = bh >> 4, h = bh & 15;

    const _Float16* Qh_ = Qhi + (size_t)bh * SEQ * HEAD_DIM;
    const _Float16* Ql_ = Qlo + (size_t)bh * SEQ * HEAD_DIM;
    const _Float16* Khg = Khi + (size_t)bh * SEQ * HEAD_DIM;
    const _Float16* Klg = Klo + (size_t)bh * SEQ * HEAD_DIM;
    const _Float16* Vtg = Vt  + (size_t)bh * HEAD_DIM * SEQ;

    // Q B-fragments per group: B[n=q=r][k=d=c*32+quad*8+j], hi and lo
    half8 qh0[2], ql0[2], qh1[2], ql1[2];
    #pragma unroll
    for (int c = 0; c < 2; ++c) {
        qh0[c] = *(const half8*)&Qh_[(size_t)(q0a + r)*64 + c*32 + quad*8];
        ql0[c] = *(const half8*)&Ql_[(size_t)(q0a + r)*64 + c*32 + quad*8];
        qh1[c] = *(const half8*)&Qh_[(size_t)(q0b + r)*64 + c*32 + quad*8];
        ql1[c] = *(const half8*)&Ql_[(size_t)(q0b + r)*64 + c*32 + quad*8];
    }

    // O^T accumulators per group: tile d = dt*16+quad*4+v, col q = r
    floatx4 ot0[4], ot1[4];
    #pragma unroll
    for (int dt = 0; dt < 4; ++dt) {
        ot0[dt] = (floatx4){0.f,0.f,0.f,0.f};
        ot1[dt] = (floatx4){0.f,0.f,0.f,0.f};
    }
    float mi0 = -1e30f, li0 = 0.f, mi1 = -1e30f, li1 = 0.f;

    const int sr = lane >> 2;             // staging: 16 rows per strip
    const int sc = (lane & 3) << 3;
    const int rb = w << 4;                // wave-uniform strip base (w*16)
    const int srow = rb + sr;             // this lane's staged row (0..63)

    // reg-staged tile: load (issue-early) and write (late, padded layout)
    half8 rg[6];
    auto stage_load = [&](int kt) {
        const int k0 = kt << 6;
        const size_t kr = (size_t)(k0 + srow)*64;
        rg[0] = *(const half8*)&Khg[kr +      sc];
        rg[1] = *(const half8*)&Khg[kr + 32 + sc];
        rg[2] = *(const half8*)&Klg[kr +      sc];
        rg[3] = *(const half8*)&Klg[kr + 32 + sc];
        const size_t vr = (size_t)srow*SEQ + k0;
        rg[4] = *(const half8*)&Vtg[vr +      sc];
        rg[5] = *(const half8*)&Vtg[vr + 32 + sc];
    };
    auto stage_write = [&]() {
        const int o = srow*KSTR + sc;
        #pragma unroll
        for (int p = 0; p < 6; ++p)
            *(half8*)&SB[p][o] = rg[p];
    };

    const int niter = 2*qb + 2;           // key tiles of 64
    stage_load(0);
    stage_write();                        // prologue: tile 0 into SB (no readers yet)

    for (int kt = 0; kt < niter; ++kt) {
        const int k0 = kt << 6;

        __syncthreads();                  // (B) tile-kt writes visible to all waves
        if (kt + 1 < niter) stage_load(kt + 1);   // latency hides under compute

        const _Float16* Kh0 = SB[0];
        const _Float16* Kh1 = SB[1];
        const _Float16* Kl0 = SB[2];
        const _Float16* Kl1 = SB[3];
        const _Float16* Vp0 = SB[4];
        const _Float16* Vp1 = SB[5];

        const bool do0 = (kt <= 2*qb);    // block-uniform

        // ---- merged S^T: read each K-fragment ONCE, feed both groups ----
        // Per-group accumulation order identical to the serial version
        // (kh0*qh, kh1*qh, kh0*ql, kh1*ql, kl0*qh, kl1*qh) -> bitwise same.
        float s0[16], s1[16];
        __builtin_amdgcn_s_setprio(1);
        #pragma unroll
        for (int sub = 0; sub < 4; ++sub) {
            const int fr = (sub*16 + r)*KSTR + quad*8;   // 80B stride
            const half8 kh0 = *(const half8*)&Kh0[fr];
            const half8 kh1 = *(const half8*)&Kh1[fr];
            const half8 kl0 = *(const half8*)&Kl0[fr];
            const half8 kl1 = *(const half8*)&Kl1[fr];
            floatx4 a0 = (floatx4){0.f,0.f,0.f,0.f};
            floatx4 a1 = (floatx4){0.f,0.f,0.f,0.f};
            a0 = __builtin_amdgcn_mfma_f32_16x16x32_f16(kh0, qh0[0], a0, 0, 0, 0);
            a1 = __builtin_amdgcn_mfma_f32_16x16x32_f16(kh0, qh1[0], a1, 0, 0, 0);
            a0 = __builtin_amdgcn_mfma_f32_16x16x32_f16(kh1, qh0[1], a0, 0, 0, 0);
            a1 = __builtin_amdgcn_mfma_f32_16x16x32_f16(kh1, qh1[1], a1, 0, 0, 0);
            a0 = __builtin_amdgcn_mfma_f32_16x16x32_f16(kh0, ql0[0], a0, 0, 0, 0);
            a1 = __builtin_amdgcn_mfma_f32_16x16x32_f16(kh0, ql1[0], a1, 0, 0, 0);
            a0 = __builtin_amdgcn_mfma_f32_16x16x32_f16(kh1, ql0[1], a0, 0, 0, 0);
            a1 = __builtin_amdgcn_mfma_f32_16x16x32_f16(kh1, ql1[1], a1, 0, 0, 0);
            a0 = __builtin_amdgcn_mfma_f32_16x16x32_f16(kl0, qh0[0], a0, 0, 0, 0);
            a1 = __builtin_amdgcn_mfma_f32_16x16x32_f16(kl0, qh1[0], a1, 0, 0, 0);
            a0 = __builtin_amdgcn_mfma_f32_16x16x32_f16(kl1, qh0[1], a0, 0, 0, 0);
            a1 = __builtin_amdgcn_mfma_f32_16x16x32_f16(kl1, qh1[1], a1, 0, 0, 0);
            #pragma unroll
            for (int v = 0; v < 4; ++v) {
                s0[sub*4 + v] = a0[v] * 0.125f;
                s1[sub*4 + v] = a1[v] * 0.125f;
            }
        }
        __builtin_amdgcn_s_setprio(0);

        // ---- per-group softmax + P + PV (serial; single Pl strip reused;
        //      per-wave DS ops are in-order so write->read->write is safe) ----
        auto finish = [&](float (&s)[16], int q0g,
                          floatx4 (&og)[4], float &mig, float &lig, bool domask) {
            if (domask) {                 // causal mask (boundary tile only)
                #pragma unroll
                for (int sub = 0; sub < 4; ++sub)
                    #pragma unroll
                    for (int v = 0; v < 4; ++v)
                        if (k0 + sub*16 + quad*4 + v > q0g + r)
                            s[sub*4 + v] = -1e30f;
            }

            // online softmax over this tile's 64 keys (per lane: q = r)
            float tm = s[0];
            #pragma unroll
            for (int i = 1; i < 16; ++i) tm = fmaxf(tm, s[i]);
            tm = fmaxf(tm, __shfl_xor(tm, 16));
            tm = fmaxf(tm, __shfl_xor(tm, 32));
            const float mn = fmaxf(mig, tm);
            const float alpha = __expf(mig - mn);
            mig = mn;
            float rs = 0.f;
            #pragma unroll
            for (int i = 0; i < 16; ++i) { s[i] = __expf(s[i] - mn); rs += s[i]; }
            rs += __shfl_xor(rs, 16);
            rs += __shfl_xor(rs, 32);
            lig = lig*alpha + rs;
            #pragma unroll
            for (int dt = 0; dt < 4; ++dt)
                #pragma unroll
                for (int v = 0; v < 4; ++v) og[dt][v] *= alpha;

            // P^T -> per-wave LDS strip [q=r][key], packed 4-wide
            #pragma unroll
            for (int sub = 0; sub < 4; ++sub) {
                half4v pk = { (_Float16)s[sub*4+0], (_Float16)s[sub*4+1],
                              (_Float16)s[sub*4+2], (_Float16)s[sub*4+3] };
                *(half4v*)&Pl[w][r*PSTR + sub*16 + quad*4] = pk;
            }

            // O^T += V^T·P : A = V^T-frag [m=d][k=key], B = P [n=q][k=key]
            __builtin_amdgcn_s_setprio(1);
            #pragma unroll
            for (int c = 0; c < 2; ++c) {
                const half8 pf = *(const half8*)&Pl[w][r*PSTR + c*32 + quad*8];
                const _Float16* Vsc = c ? Vp1 : Vp0;
                #pragma unroll
                for (int dt = 0; dt < 4; ++dt) {
                    const half8 vf = *(const half8*)&Vsc[(dt*16 + r)*KSTR + quad*8];
                    og[dt] = __builtin_amdgcn_mfma_f32_16x16x32_f16(vf, pf, og[dt], 0, 0, 0);
                }
            }
            __builtin_amdgcn_s_setprio(0);
        };

        if (do0) finish(s0, q0a, ot0, mi0, li0, kt == 2*qb);
        finish(s1, q0b, ot1, mi1, li1, kt == 2*qb + 1);

        if (kt + 1 < niter) {
            __syncthreads();              // (A) all waves' reads of SB done
            stage_write();                // overwrite with tile kt+1
        }
    }

    // epilogue: normalize, write AO [b][s=q][h*64 + d] (8B stores)
    {
        const float inv0 = 1.0f / li0;
        const int q = q0a + r;
        #pragma unroll
        for (int dt = 0; dt < 4; ++dt) {
            half4v o = { (_Float16)(ot0[dt][0]*inv0), (_Float16)(ot0[dt][1]*inv0),
                         (_Float16)(ot0[dt][2]*inv0), (_Float16)(ot0[dt][3]*inv0) };
            *(half4v*)&AO[((size_t)(b*SEQ + q))*D_MODEL + h*HEAD_DIM + dt*16 + quad*4] = o;
        }
    }
    {
        const float inv1 = 1.0f / li1;
        const int q = q0b + r;
        #pragma unroll
        for (int dt = 0; dt < 4; ++dt) {
            half4v o = { (_Float16)(ot1[dt][0]*inv1), (_Float16)(ot1[dt][1]*inv1),
                         (_Float16)(ot1[dt][2]*inv1), (_Float16)(ot1[dt][3]*inv1) };
            *(half4v*)&AO[((size_t)(b*SEQ + q))*D_MODEL + h*HEAD_DIM + dt*16 + quad*4] = o;
        }
    }
}

// ---------------------------------------------------------------------------
extern "C" void kernel_launch(void* const* d_in, const int* in_sizes, int n_in,
                              void* d_out, int out_size, void* d_ws, size_t ws_size,
                              hipStream_t stream) {
    const float* x  = (const float*)d_in[0];
    const float* qw = (const float*)d_in[1];
    const float* kw = (const float*)d_in[2];
    const float* vw = (const float*)d_in[3];
    const float* ow = (const float*)d_in[4];
    float* out = (float*)d_out;

    // workspace layout (_Float16 counts), total ~147.3 MB
    _Float16* xh  = (_Float16*)d_ws;
    _Float16* xl  = xh  + (size_t)MROWS * D_MODEL;
    _Float16* qwh = xl  + (size_t)MROWS * D_MODEL;
    _Float16* qwl = qwh + (size_t)D_MODEL * D_MODEL;
    _Float16* kwh = qwl + (size_t)D_MODEL * D_MODEL;
    _Float16* kwl = kwh + (size_t)D_MODEL * D_MODEL;
    _Float16* vwh = kwl + (size_t)D_MODEL * D_MODEL;
    _Float16* owh = vwh + (size_t)D_MODEL * D_MODEL;
    _Float16* Qhi = owh + (size_t)D_MODEL * D_MODEL;
    _Float16* Qlo = Qhi + (size_t)MROWS * D_MODEL;
    _Float16* Khi = Qlo + (size_t)MROWS * D_MODEL;
    _Float16* Klo = Khi + (size_t)MROWS * D_MODEL;
    _Float16* Vt  = Klo + (size_t)MROWS * D_MODEL;
    _Float16* AO  = Vt  + (size_t)MROWS * D_MODEL;
    float2*   tab = (float2*)(AO + (size_t)MROWS * D_MODEL);

    rope_table<<<(SEQ*32)/256, 256, 0, stream>>>(tab);

    const int nx4 = MROWS * D_MODEL / 4;
    f32_split_f16<<<nx4/256, 256, 0, stream>>>(x, xh, xl, nx4);
    conv_weights<<<(4*262144)/256, 256, 0, stream>>>(qw, kw, vw, ow,
                                                     qwh, qwl, kwh, kwl, vwh, owh);

    // split dispatches: QK (bx 0..15), V (bx 16..23) — keeps flash_attn the
    // longest dispatch so rocprof's top-5 shows its counters.
    gemm_qkv<<<64*16, 256, 0, stream>>>(xh, xl, qwh, qwl, kwh, kwl, vwh,
                                        Qhi, Qlo, Khi, Klo, Vt, tab, 0, 16);
    gemm_qkv<<<64*8, 256, 0, stream>>>(xh, xl, qwh, qwl, kwh, kwl, vwh,
                                       Qhi, Qlo, Khi, Klo, Vt, tab, 16, 8);

    flash_attn<<<BH * (SEQ/128), 256, 0, stream>>>(Qhi, Qlo, Khi, Klo, Vt, AO);

    gemm_bt<<<(MROWS/128)*(D_MODEL/128), 256, 0, stream>>>(AO, owh, out,
                                                           MROWS, D_MODEL, D_MODEL);
}

// Round 14
// 360.330 us; speedup vs baseline: 1.2673x; 1.2673x over previous
//
#include <hip/hip_runtime.h>
#include <hip/hip_bf16.h>
#include <cstdint>
#include <cstddef>

#define D_MODEL   1024
#define NUM_HEADS 16
#define HEAD_DIM  64
#define SEQ       2048
#define BATCH     4
#define BH        (BATCH*NUM_HEADS)   // 64
#define MROWS     (BATCH*SEQ)         // 8192

typedef _Float16 half8  __attribute__((ext_vector_type(8)));
typedef _Float16 half4v __attribute__((ext_vector_type(4)));
typedef float    floatx4 __attribute__((ext_vector_type(4)));

// ---------------------------------------------------------------------------
// async global -> LDS, 16 bytes per lane. LDS base must be wave-uniform;
// HW writes lds_base + lane*16 (LDS side contiguous; global side per-lane).
// ---------------------------------------------------------------------------
__device__ inline void gld_lds16(const void* g, void* l) {
    __builtin_amdgcn_global_load_lds(
        (__attribute__((address_space(1))) void*)g,
        (__attribute__((address_space(3))) void*)l,
        16, 0, 0);
}

// ---------------------------------------------------------------------------
// RoPE cos/sin table [s][p], p in [0,32): angle = s * 10000^(-p/32), fp64.
// ---------------------------------------------------------------------------
__global__ void rope_table(float2* __restrict__ tab) {
    const int i = blockIdx.x * blockDim.x + threadIdx.x;   // SEQ*32
    const int p = i & 31, s = i >> 5;
    const double inv = pow(10000.0, -(double)p / 32.0);
    const double ang = (double)s * inv;
    tab[i] = make_float2((float)cos(ang), (float)sin(ang));
}

// ---------------------------------------------------------------------------
// fp32 -> split f16 (hi + lo residual) for x, 4-wide. v ~= hi + lo to ~2^-22.
// ---------------------------------------------------------------------------
__global__ void f32_split_f16(const float* __restrict__ in,
                              _Float16* __restrict__ hi,
                              _Float16* __restrict__ lo, int n4) {
    int i = blockIdx.x * blockDim.x + threadIdx.x;
    if (i >= n4) return;
    float4 v = ((const float4*)in)[i];
    half4v h = { (_Float16)v.x, (_Float16)v.y, (_Float16)v.z, (_Float16)v.w };
    half4v l = { (_Float16)(v.x - (float)h.x), (_Float16)(v.y - (float)h.y),
                 (_Float16)(v.z - (float)h.z), (_Float16)(v.w - (float)h.w) };
    ((half4v*)hi)[i] = h;
    ((half4v*)lo)[i] = l;
}

// ---------------------------------------------------------------------------
// All 4 weight converts in one dispatch: qw,kw -> split hi/lo; vw,ow -> hi.
// ---------------------------------------------------------------------------
__global__ void conv_weights(const float* __restrict__ qw, const float* __restrict__ kw,
                             const float* __restrict__ vw, const float* __restrict__ ow,
                             _Float16* __restrict__ qwh, _Float16* __restrict__ qwl,
                             _Float16* __restrict__ kwh, _Float16* __restrict__ kwl,
                             _Float16* __restrict__ vwh, _Float16* __restrict__ owh) {
    const int i = blockIdx.x * blockDim.x + threadIdx.x;
    const int which = i >> 18;              // 262144 float4 per tensor
    const int j = i & 262143;
    const float4 v = ((const float4*)(which == 0 ? qw : which == 1 ? kw :
                                      which == 2 ? vw : ow))[j];
    half4v h = { (_Float16)v.x, (_Float16)v.y, (_Float16)v.z, (_Float16)v.w };
    if (which < 2) {
        half4v l = { (_Float16)(v.x - (float)h.x), (_Float16)(v.y - (float)h.y),
                     (_Float16)(v.z - (float)h.z), (_Float16)(v.w - (float)h.w) };
        ((half4v*)(which ? kwh : qwh))[j] = h;
        ((half4v*)(which ? kwl : qwl))[j] = l;
    } else {
        ((half4v*)(which == 2 ? vwh : owh))[j] = h;
    }
}

// ---------------------------------------------------------------------------
// Plain GEMM: C[m,n] = sum_k A[m,k]*B[n,k], fp32 out. Output projection.
// Double-buffered LDS (2x16KB), ONE barrier per K-step.
// ---------------------------------------------------------------------------
__global__ __launch_bounds__(256)
void gemm_bt(const _Float16* __restrict__ A, const _Float16* __restrict__ B,
             float* __restrict__ Cout, int M, int N, int K) {
    __shared__ _Float16 AB[2][2][128*32];    // [buf][A/B] 32KB

    const int nb  = N >> 7;
    const int nwg = gridDim.x;
    int lb = blockIdx.x;
    if ((nwg & 7) == 0)                      // chunked XCD swizzle (m157)
        lb = (blockIdx.x & 7) * (nwg >> 3) + (blockIdx.x >> 3);
    const int bx = lb % nb;
    const int by = lb / nb;
    const int m0 = by << 7, n0 = bx << 7;

    const int t    = threadIdx.x;
    const int w    = t >> 6;
    const int lane = t & 63;
    const int r    = lane & 15;
    const int quad = lane >> 4;
    const int wm   = (w >> 1) << 6;
    const int wn   = (w & 1) << 6;

    const int srow = lane >> 2;
    const int scol = (lane & 3) << 3;

    floatx4 acc[4][4];
    #pragma unroll
    for (int i = 0; i < 4; i++)
        #pragma unroll
        for (int j = 0; j < 4; j++)
            acc[i][j] = (floatx4){0.f, 0.f, 0.f, 0.f};

    auto stageAB = [&](int buf, int kk) {
        #pragma unroll
        for (int p = 0; p < 2; ++p) {
            const int rbase = p*64 + w*16;
            gld_lds16(&A[(size_t)(m0 + rbase + srow)*K + kk + scol], &AB[buf][0][rbase*32]);
            gld_lds16(&B[(size_t)(n0 + rbase + srow)*K + kk + scol], &AB[buf][1][rbase*32]);
        }
    };

    stageAB(0, 0);                           // prologue
    int cur = 0;
    for (int k0 = 0; k0 < K; k0 += 32) {
        __syncthreads();                     // stage(k0,cur) landed; prev reads done
        if (k0 + 32 < K) stageAB(cur ^ 1, k0 + 32);   // hides under reads+MFMA

        const _Float16* As = AB[cur][0];
        const _Float16* Bs = AB[cur][1];
        half8 af[4], bf[4];
        #pragma unroll
        for (int i = 0; i < 4; i++)
            af[i] = *(const half8*)&As[(wm + i*16 + r)*32 + quad*8];
        #pragma unroll
        for (int j = 0; j < 4; j++)
            bf[j] = *(const half8*)&Bs[(wn + j*16 + r)*32 + quad*8];

        #pragma unroll
        for (int i = 0; i < 4; i++)
            #pragma unroll
            for (int j = 0; j < 4; j++)
                acc[i][j] = __builtin_amdgcn_mfma_f32_16x16x32_f16(
                                af[i], bf[j], acc[i][j], 0, 0, 0);
        cur ^= 1;
    }

    #pragma unroll
    for (int i = 0; i < 4; i++)
        #pragma unroll
        for (int j = 0; j < 4; j++)
            #pragma unroll
            for (int v = 0; v < 4; v++) {
                const int m = m0 + wm + i*16 + quad*4 + v;
                const int n = n0 + wn + j*16 + r;
                Cout[(size_t)m*N + n] = acc[i][j][v];
            }
}

// ---------------------------------------------------------------------------
// Fused Q/K/V projection — split into QK / V dispatches (kept: flash stays
// visible in rocprof top-5). Kernel body unchanged; bx = bxoff + lb%nt.
// ---------------------------------------------------------------------------
__global__ __launch_bounds__(256)
void gemm_qkv(const _Float16* __restrict__ Axh, const _Float16* __restrict__ Axl,
              const _Float16* __restrict__ qwh, const _Float16* __restrict__ qwl,
              const _Float16* __restrict__ kwh, const _Float16* __restrict__ kwl,
              const _Float16* __restrict__ vwh,
              _Float16* __restrict__ Qhi, _Float16* __restrict__ Qlo,
              _Float16* __restrict__ Khi, _Float16* __restrict__ Klo,
              _Float16* __restrict__ Vt,  const float2* __restrict__ tab,
              int bxoff, int nt) {
    __shared__ _Float16 smem[2][4][4096];  // 64KB: [buf][plane: Ah,Al,Bh,Bl][8KB]

    // chunked XCD swizzle (nwg %8==0): consecutive lb chunks per XCD.
    const int nwg = gridDim.x;
    const int lb  = (blockIdx.x & 7) * (nwg >> 3) + (blockIdx.x >> 3);
    const int bx  = bxoff + lb % nt;
    const int by  = lb / nt;
    const int wt  = bx >> 3;               // 0=Q, 1=K, 2=V
    const int n0  = (bx & 7) << 7;         // within this weight's 1024 cols
    const int m0  = by << 7;

    const _Float16* Bh = (wt == 0) ? qwh : (wt == 1) ? kwh : vwh;
    const _Float16* Bl = (wt == 0) ? qwl : kwl;      // unused when wt==2

    const int t    = threadIdx.x;
    const int w    = t >> 6;
    const int lane = t & 63;
    const int r    = lane & 15;
    const int quad = lane >> 4;
    const int wm   = (w >> 1) << 6;
    const int wn   = (w & 1) << 6;

    const int srow = lane >> 2;
    const int scol = (lane & 3) << 3;

    floatx4 acc[4][4];
    #pragma unroll
    for (int i = 0; i < 4; i++)
        #pragma unroll
        for (int j = 0; j < 4; j++)
            acc[i][j] = (floatx4){0.f, 0.f, 0.f, 0.f};

    auto stage_k = [&](int buf, int kk) {
        #pragma unroll
        for (int p = 0; p < 2; ++p) {
            const int rbase = p*64 + w*16;
            const size_t ga = (size_t)(m0 + rbase + srow)*1024 + kk + scol;
            const size_t gb = (size_t)(n0 + rbase + srow)*1024 + kk + scol;
            gld_lds16(&Axh[ga], &smem[buf][0][rbase*32]);
            gld_lds16(&Bh [gb], &smem[buf][2][rbase*32]);
            if (wt < 2) {
                gld_lds16(&Axl[ga], &smem[buf][1][rbase*32]);
                gld_lds16(&Bl [gb], &smem[buf][3][rbase*32]);
            }
        }
    };

    stage_k(0, 0);                         // prologue
    int cur = 0;
    for (int k0 = 0; k0 < 1024; k0 += 32) {
        __syncthreads();                   // stage(k0)->buf[cur] landed; prev reads done
        if (k0 + 32 < 1024) stage_k(cur ^ 1, k0 + 32);   // max-distance prefetch

        const _Float16* Ash = smem[cur][0];
        const _Float16* Asl = smem[cur][1];
        const _Float16* Bsh = smem[cur][2];
        const _Float16* Bsl = smem[cur][3];

        half8 ah[4], bh[4], al[4], bl[4];
        #pragma unroll
        for (int i = 0; i < 4; i++)
            ah[i] = *(const half8*)&Ash[(wm + i*16 + r)*32 + quad*8];
        #pragma unroll
        for (int j = 0; j < 4; j++)
            bh[j] = *(const half8*)&Bsh[(wn + j*16 + r)*32 + quad*8];
        if (wt < 2) {
            #pragma unroll
            for (int i = 0; i < 4; i++)
                al[i] = *(const half8*)&Asl[(wm + i*16 + r)*32 + quad*8];
            #pragma unroll
            for (int j = 0; j < 4; j++)
                bl[j] = *(const half8*)&Bsl[(wn + j*16 + r)*32 + quad*8];
        }

        if (wt < 2) {
            #pragma unroll
            for (int i = 0; i < 4; i++)
                #pragma unroll
                for (int j = 0; j < 4; j++) {
                    acc[i][j] = __builtin_amdgcn_mfma_f32_16x16x32_f16(
                                    ah[i], bh[j], acc[i][j], 0, 0, 0);
                    acc[i][j] = __builtin_amdgcn_mfma_f32_16x16x32_f16(
                                    ah[i], bl[j], acc[i][j], 0, 0, 0);
                    acc[i][j] = __builtin_amdgcn_mfma_f32_16x16x32_f16(
                                    al[i], bh[j], acc[i][j], 0, 0, 0);
                }
        } else {
            #pragma unroll
            for (int i = 0; i < 4; i++)
                #pragma unroll
                for (int j = 0; j < 4; j++)
                    acc[i][j] = __builtin_amdgcn_mfma_f32_16x16x32_f16(
                                    ah[i], bh[j], acc[i][j], 0, 0, 0);
        }
        cur ^= 1;
    }

    // ----- epilogue: per-wave LDS transpose + wide stores -----
    __syncthreads();                       // K-loop LDS traffic done; reuse as scratch
    float* sc = (float*)&smem[0][0][0] + w*1088;   // 16 rows x stride 68 fp32, per wave
    const int g  = lane & 7;               // 8-col group
    const int rw = lane >> 3;              // 0..7
    const int hh = (n0 + wn) >> 6;         // head fixed per wave (n0%128==0, wn 0/64)

    if (wt < 2) {
        _Float16* Chi = wt ? Khi : Qhi;
        _Float16* Clo = wt ? Klo : Qlo;
        #pragma unroll
        for (int i = 0; i < 4; i++) {
            #pragma unroll
            for (int j = 0; j < 4; j++)
                #pragma unroll
                for (int v = 0; v < 4; v++)
                    sc[(quad*4 + v)*68 + j*16 + r] = acc[i][j][v];
            // per-wave region; same-wave DS ops are in-order (Pl pattern)
            #pragma unroll
            for (int rg = 0; rg < 2; rg++) {
                const int row = rw + rg*8;
                const int m   = m0 + wm + i*16 + row;
                const int bb  = m >> 11, s_ = m & 2047;
                const float4 va = *(const float4*)&sc[row*68 + g*8];
                const float4 vb = *(const float4*)&sc[row*68 + g*8 + 4];
                const float vv[8] = {va.x, va.y, va.z, va.w,
                                     vb.x, vb.y, vb.z, vb.w};
                half8 hv, lv;
                #pragma unroll
                for (int p2 = 0; p2 < 4; p2++) {
                    const float2 cs = tab[s_*32 + g*4 + p2];
                    const float e0 = vv[2*p2], o0 = vv[2*p2+1];
                    const float re = e0*cs.x - o0*cs.y;
                    const float ro = e0*cs.y + o0*cs.x;
                    const _Float16 rh = (_Float16)re;
                    const _Float16 oh = (_Float16)ro;
                    hv[2*p2]   = rh; lv[2*p2]   = (_Float16)(re - (float)rh);
                    hv[2*p2+1] = oh; lv[2*p2+1] = (_Float16)(ro - (float)oh);
                }
                const size_t idx = ((((size_t)bb*NUM_HEADS + hh)*SEQ + s_) << 6) + g*8;
                *(half8*)&Chi[idx] = hv;
                *(half8*)&Clo[idx] = lv;
            }
        }
    } else {
        const int d = lane;                // 0..63, col within wave's 64
        #pragma unroll
        for (int i = 0; i < 4; i++) {
            #pragma unroll
            for (int j = 0; j < 4; j++)
                #pragma unroll
                for (int v = 0; v < 4; v++)
                    sc[(quad*4 + v)*68 + j*16 + r] = acc[i][j][v];
            #pragma unroll
            for (int rg = 0; rg < 2; rg++) {
                const int m  = m0 + wm + i*16 + rg*8;
                const int bb = m >> 11, s_ = m & 2047;
                half8 ov;
                #pragma unroll
                for (int rr = 0; rr < 8; rr++)
                    ov[rr] = (_Float16)sc[(rg*8 + rr)*68 + d];
                *(half8*)&Vt[((((size_t)bb*NUM_HEADS + hh)*HEAD_DIM + d) << 11) + s_] = ov;
            }
        }
    }
}

// ---------------------------------------------------------------------------
// Causal flash attention — REVERTED to round-11-exact (best measured flash:
// 123.5us, total 364.2). R13's merged-K + __launch_bounds__(256,4) forced
// VGPR 88->64 -> massive scratch spill (WRITE_SIZE 16->303MB) -> 195us.
// Lesson (rule #20/#6): a waves-per-EU bound below the kernel's natural
// register need converts an occupancy guard into a spill cliff.
// Structure: QBLK=128, two serial 16-q groups per staged tile; single-buffer
// SB (39.9KB -> 4 blocks/CU); reg-staged T14 issue-early/write-late.
// ---------------------------------------------------------------------------
#define PSTR 72     // P strip stride in f16
#define KSTR 40     // K/V plane row stride in f16
__global__ __launch_bounds__(256)
void flash_attn(const _Float16* __restrict__ Qhi, const _Float16* __restrict__ Qlo,
                const _Float16* __restrict__ Khi, const _Float16* __restrict__ Klo,
                const _Float16* __restrict__ Vt,  _Float16* __restrict__ AO) {
    // SB[plane][64*KSTR]: planes 0/1 = K hi d[0,32)/d[32,64),
    // 2/3 = K lo, 4/5 = V^T keys [0,32)/[32,64). 30KB, single-buffered.
    __shared__ _Float16 SB[6][64*KSTR];
    __shared__ _Float16 Pl[4][16*PSTR];

    const int t    = threadIdx.x;
    const int w    = t >> 6;
    const int lane = t & 63;
    const int r    = lane & 15;
    const int quad = lane >> 4;

    const int bx = blockIdx.x;
    const int bh = bx & 63;                 // 64 bh, fastest
    const int qb = 15 - (bx >> 6);          // 16 q-blocks of 128, longest first
    const int Q0 = qb << 7;
    const int q0a = Q0 + w*16;              // group 0 rows
    const int q0b = Q0 + 64 + w*16;         // group 1 rows
    const int b  = bh >> 4, h = bh & 15;

    const _Float16* Qh_ = Qhi + (size_t)bh * SEQ * HEAD_DIM;
    const _Float16* Ql_ = Qlo + (size_t)bh * SEQ * HEAD_DIM;
    const _Float16* Khg = Khi + (size_t)bh * SEQ * HEAD_DIM;
    const _Float16* Klg = Klo + (size_t)bh * SEQ * HEAD_DIM;
    const _Float16* Vtg = Vt  + (size_t)bh * HEAD_DIM * SEQ;

    // Q B-fragments per group: B[n=q=r][k=d=c*32+quad*8+j], hi and lo
    half8 qh0[2], ql0[2], qh1[2], ql1[2];
    #pragma unroll
    for (int c = 0; c < 2; ++c) {
        qh0[c] = *(const half8*)&Qh_[(size_t)(q0a + r)*64 + c*32 + quad*8];
        ql0[c] = *(const half8*)&Ql_[(size_t)(q0a + r)*64 + c*32 + quad*8];
        qh1[c] = *(const half8*)&Qh_[(size_t)(q0b + r)*64 + c*32 + quad*8];
        ql1[c] = *(const half8*)&Ql_[(size_t)(q0b + r)*64 + c*32 + quad*8];
    }

    // O^T accumulators per group: tile d = dt*16+quad*4+v, col q = r
    floatx4 ot0[4], ot1[4];
    #pragma unroll
    for (int dt = 0; dt < 4; ++dt) {
        ot0[dt] = (floatx4){0.f,0.f,0.f,0.f};
        ot1[dt] = (floatx4){0.f,0.f,0.f,0.f};
    }
    float mi0 = -1e30f, li0 = 0.f, mi1 = -1e30f, li1 = 0.f;

    const int sr = lane >> 2;             // staging: 16 rows per strip
    const int sc = (lane & 3) << 3;
    const int rb = w << 4;                // wave-uniform strip base (w*16)
    const int srow = rb + sr;             // this lane's staged row (0..63)

    // reg-staged tile: load (issue-early) and write (late, padded layout)
    half8 rg[6];
    auto stage_load = [&](int kt) {
        const int k0 = kt << 6;
        const size_t kr = (size_t)(k0 + srow)*64;
        rg[0] = *(const half8*)&Khg[kr +      sc];
        rg[1] = *(const half8*)&Khg[kr + 32 + sc];
        rg[2] = *(const half8*)&Klg[kr +      sc];
        rg[3] = *(const half8*)&Klg[kr + 32 + sc];
        const size_t vr = (size_t)srow*SEQ + k0;
        rg[4] = *(const half8*)&Vtg[vr +      sc];
        rg[5] = *(const half8*)&Vtg[vr + 32 + sc];
    };
    auto stage_write = [&]() {
        const int o = srow*KSTR + sc;
        #pragma unroll
        for (int p = 0; p < 6; ++p)
            *(half8*)&SB[p][o] = rg[p];
    };

    const int niter = 2*qb + 2;           // key tiles of 64
    stage_load(0);
    stage_write();                        // prologue: tile 0 into SB (no readers yet)

    for (int kt = 0; kt < niter; ++kt) {
        const int k0 = kt << 6;

        __syncthreads();                  // (B) tile-kt writes visible to all waves
        if (kt + 1 < niter) stage_load(kt + 1);   // latency hides under compute

        const _Float16* Kh0 = SB[0];
        const _Float16* Kh1 = SB[1];
        const _Float16* Kl0 = SB[2];
        const _Float16* Kl1 = SB[3];
        const _Float16* Vp0 = SB[4];
        const _Float16* Vp1 = SB[5];

        // process one 16-q group against the staged 64-key tile
        auto group = [&](int q0g, const half8 (&qhg)[2], const half8 (&qlg)[2],
                         floatx4 (&og)[4], float &mig, float &lig, bool domask) {
            // S^T = K·Q^T : 16 scores per lane (key = sub*16+quad*4+v, q = r)
            float s[16];
            __builtin_amdgcn_s_setprio(1);
            #pragma unroll
            for (int sub = 0; sub < 4; ++sub) {
                floatx4 a = (floatx4){0.f,0.f,0.f,0.f};
                const int fr = (sub*16 + r)*KSTR + quad*8;   // 80B stride
                const half8 kh0 = *(const half8*)&Kh0[fr];
                const half8 kh1 = *(const half8*)&Kh1[fr];
                const half8 kl0 = *(const half8*)&Kl0[fr];
                const half8 kl1 = *(const half8*)&Kl1[fr];
                a = __builtin_amdgcn_mfma_f32_16x16x32_f16(kh0, qhg[0], a, 0, 0, 0);
                a = __builtin_amdgcn_mfma_f32_16x16x32_f16(kh1, qhg[1], a, 0, 0, 0);
                a = __builtin_amdgcn_mfma_f32_16x16x32_f16(kh0, qlg[0], a, 0, 0, 0);
                a = __builtin_amdgcn_mfma_f32_16x16x32_f16(kh1, qlg[1], a, 0, 0, 0);
                a = __builtin_amdgcn_mfma_f32_16x16x32_f16(kl0, qhg[0], a, 0, 0, 0);
                a = __builtin_amdgcn_mfma_f32_16x16x32_f16(kl1, qhg[1], a, 0, 0, 0);
                #pragma unroll
                for (int v = 0; v < 4; ++v) s[sub*4 + v] = a[v] * 0.125f;
            }
            __builtin_amdgcn_s_setprio(0);

            if (domask) {                 // causal mask (boundary tile only)
                #pragma unroll
                for (int sub = 0; sub < 4; ++sub)
                    #pragma unroll
                    for (int v = 0; v < 4; ++v)
                        if (k0 + sub*16 + quad*4 + v > q0g + r)
                            s[sub*4 + v] = -1e30f;
            }

            // online softmax over this tile's 64 keys (per lane: q = r)
            float tm = s[0];
            #pragma unroll
            for (int i = 1; i < 16; ++i) tm = fmaxf(tm, s[i]);
            tm = fmaxf(tm, __shfl_xor(tm, 16));
            tm = fmaxf(tm, __shfl_xor(tm, 32));
            const float mn = fmaxf(mig, tm);
            const float alpha = __expf(mig - mn);
            mig = mn;
            float rs = 0.f;
            #pragma unroll
            for (int i = 0; i < 16; ++i) { s[i] = __expf(s[i] - mn); rs += s[i]; }
            rs += __shfl_xor(rs, 16);
            rs += __shfl_xor(rs, 32);
            lig = lig*alpha + rs;
            #pragma unroll
            for (int dt = 0; dt < 4; ++dt)
                #pragma unroll
                for (int v = 0; v < 4; ++v) og[dt][v] *= alpha;

            // P^T -> per-wave LDS strip [q=r][key], packed 4-wide
            #pragma unroll
            for (int sub = 0; sub < 4; ++sub) {
                half4v pk = { (_Float16)s[sub*4+0], (_Float16)s[sub*4+1],
                              (_Float16)s[sub*4+2], (_Float16)s[sub*4+3] };
                *(half4v*)&Pl[w][r*PSTR + sub*16 + quad*4] = pk;
            }
            // (same-wave write->read: compiler inserts lgkmcnt wait, no barrier)

            // O^T += V^T·P : A = V^T-frag [m=d][k=key], B = P [n=q][k=key]
            __builtin_amdgcn_s_setprio(1);
            #pragma unroll
            for (int c = 0; c < 2; ++c) {
                const half8 pf = *(const half8*)&Pl[w][r*PSTR + c*32 + quad*8];
                const _Float16* Vsc = c ? Vp1 : Vp0;
                #pragma unroll
                for (int dt = 0; dt < 4; ++dt) {
                    const half8 vf = *(const half8*)&Vsc[(dt*16 + r)*KSTR + quad*8];
                    og[dt] = __builtin_amdgcn_mfma_f32_16x16x32_f16(vf, pf, og[dt], 0, 0, 0);
                }
            }
            __builtin_amdgcn_s_setprio(0);
        };

        if (kt <= 2*qb) group(q0a, qh0, ql0, ot0, mi0, li0, kt == 2*qb);
        group(q0b, qh1, ql1, ot1, mi1, li1, kt == 2*qb + 1);

        if (kt + 1 < niter) {
            __syncthreads();              // (A) all waves' reads of SB done
            stage_write();                // overwrite with tile kt+1
        }
    }

    // epilogue: normalize, write AO [b][s=q][h*64 + d] (8B stores)
    {
        const float inv0 = 1.0f / li0;
        const int q = q0a + r;
        #pragma unroll
        for (int dt = 0; dt < 4; ++dt) {
            half4v o = { (_Float16)(ot0[dt][0]*inv0), (_Float16)(ot0[dt][1]*inv0),
                         (_Float16)(ot0[dt][2]*inv0), (_Float16)(ot0[dt][3]*inv0) };
            *(half4v*)&AO[((size_t)(b*SEQ + q))*D_MODEL + h*HEAD_DIM + dt*16 + quad*4] = o;
        }
    }
    {
        const float inv1 = 1.0f / li1;
        const int q = q0b + r;
        #pragma unroll
        for (int dt = 0; dt < 4; ++dt) {
            half4v o = { (_Float16)(ot1[dt][0]*inv1), (_Float16)(ot1[dt][1]*inv1),
                         (_Float16)(ot1[dt][2]*inv1), (_Float16)(ot1[dt][3]*inv1) };
            *(half4v*)&AO[((size_t)(b*SEQ + q))*D_MODEL + h*HEAD_DIM + dt*16 + quad*4] = o;
        }
    }
}

// ---------------------------------------------------------------------------
extern "C" void kernel_launch(void* const* d_in, const int* in_sizes, int n_in,
                              void* d_out, int out_size, void* d_ws, size_t ws_size,
                              hipStream_t stream) {
    const float* x  = (const float*)d_in[0];
    const float* qw = (const float*)d_in[1];
    const float* kw = (const float*)d_in[2];
    const float* vw = (const float*)d_in[3];
    const float* ow = (const float*)d_in[4];
    float* out = (float*)d_out;

    // workspace layout (_Float16 counts), total ~147.3 MB
    _Float16* xh  = (_Float16*)d_ws;
    _Float16* xl  = xh  + (size_t)MROWS * D_MODEL;
    _Float16* qwh = xl  + (size_t)MROWS * D_MODEL;
    _Float16* qwl = qwh + (size_t)D_MODEL * D_MODEL;
    _Float16* kwh = qwl + (size_t)D_MODEL * D_MODEL;
    _Float16* kwl = kwh + (size_t)D_MODEL * D_MODEL;
    _Float16* vwh = kwl + (size_t)D_MODEL * D_MODEL;
    _Float16* owh = vwh + (size_t)D_MODEL * D_MODEL;
    _Float16* Qhi = owh + (size_t)D_MODEL * D_MODEL;
    _Float16* Qlo = Qhi + (size_t)MROWS * D_MODEL;
    _Float16* Khi = Qlo + (size_t)MROWS * D_MODEL;
    _Float16* Klo = Khi + (size_t)MROWS * D_MODEL;
    _Float16* Vt  = Klo + (size_t)MROWS * D_MODEL;
    _Float16* AO  = Vt  + (size_t)MROWS * D_MODEL;
    float2*   tab = (float2*)(AO + (size_t)MROWS * D_MODEL);

    rope_table<<<(SEQ*32)/256, 256, 0, stream>>>(tab);

    const int nx4 = MROWS * D_MODEL / 4;
    f32_split_f16<<<nx4/256, 256, 0, stream>>>(x, xh, xl, nx4);
    conv_weights<<<(4*262144)/256, 256, 0, stream>>>(qw, kw, vw, ow,
                                                     qwh, qwl, kwh, kwl, vwh, owh);

    // split dispatches: QK (bx 0..15), V (bx 16..23) — keeps flash_attn the
    // longest dispatch so rocprof's top-5 shows its counters.
    gemm_qkv<<<64*16, 256, 0, stream>>>(xh, xl, qwh, qwl, kwh, kwl, vwh,
                                        Qhi, Qlo, Khi, Klo, Vt, tab, 0, 16);
    gemm_qkv<<<64*8, 256, 0, stream>>>(xh, xl, qwh, qwl, kwh, kwl, vwh,
                                       Qhi, Qlo, Khi, Klo, Vt, tab, 16, 8);

    flash_attn<<<BH * (SEQ/128), 256, 0, stream>>>(Qhi, Qlo, Khi, Klo, Vt, AO);

    gemm_bt<<<(MROWS/128)*(D_MODEL/128), 256, 0, stream>>>(AO, owh, out,
                                                           MROWS, D_MODEL, D_MODEL);
}